// Round 7
// baseline (100.721 us; speedup 1.0000x reference)
//
#include <hip/hip_runtime.h>
#include <hip/hip_bf16.h>

// Sparse4DHead1st deformable aggregation + output_proj + concat.
// Inputs (fp32): fm0..fm3, points_2d, weights, instance_feature, w_proj, b_proj
// Output (fp32): [1, 900, 512] = concat(acc @ w_proj + b, instance_feature)
//
// Round 7: fix round-6's units bug (meta offsets mixed element-base with
// pixel-index -> int32 overflow -> device fault). Segment bases now in
// PIXEL units; byte offsets max out at 45.9 MB, well within int32.

#define A_TOT 900
#define P_PTS 13
#define N_CAM 6
#define C_CH  256
#define N_GRP 8
#define N_LVL 4
#define N_PC  (P_PTS * N_CAM)    // 78
#define N_SAMP (A_TOT * N_PC * N_LVL)   // 280,800

// bf16 fm segment sizes (elements)
#define S0 17301504   // 6*64*176*256
#define S1 4325376    // 6*32*88*256
#define S2 1081344    // 6*16*44*256
#define S3 270336     // 6*8*22*256
#define S_TOT (S0 + S1 + S2 + S3)            // 22,978,560 elts
// segment bases in PIXELS (element base / 256)
#define PB0 0
#define PB1 67584     // S0/256
#define PB2 84480     // (S0+S1)/256
#define PB3 88704     // (S0+S1+S2)/256
#define FMW_BYTES ((size_t)S_TOT * 2)        // 45,957,120
#define ACC_BYTES ((size_t)A_TOT * C_CH * 4) //    921,600
#define METAI_BYTES ((size_t)N_SAMP * 16)    //  4,492,800
#define METAW_BYTES ((size_t)N_SAMP * 16)    //  4,492,800
#define WS_MID  (FMW_BYTES)                               // r4 fused path
#define WS_FULL (FMW_BYTES + ACC_BYTES + METAI_BYTES + METAW_BYTES) // 55,864,320

#define TM 8   // anchors per proj m-tile

__device__ __forceinline__ float bf2f(unsigned short u) {
    unsigned int t = ((unsigned int)u) << 16;
    float f;
    __builtin_memcpy(&f, &t, 4);
    return f;
}
__device__ __forceinline__ float bflo(unsigned int u) {   // low bf16 of packed u32
    unsigned int t = u << 16; float f; __builtin_memcpy(&f, &t, 4); return f;
}
__device__ __forceinline__ float bfhi(unsigned int u) {   // high bf16 of packed u32
    unsigned int t = u & 0xffff0000u; float f; __builtin_memcpy(&f, &t, 4); return f;
}
__device__ __forceinline__ unsigned short f2b(float x) {
    __hip_bfloat16 h = __float2bfloat16(x);   // RNE
    unsigned short b;
    __builtin_memcpy(&b, &h, 2);
    return b;
}

// ---------------- prepass 1: fp32 -> bf16 ----------------
__global__ __launch_bounds__(256) void convert_bf16_kernel(
    const float* __restrict__ f0, const float* __restrict__ f1,
    const float* __restrict__ f2, const float* __restrict__ f3,
    unsigned short* __restrict__ out)
{
    const size_t n8 = S_TOT / 8;
    for (size_t i = (size_t)blockIdx.x * blockDim.x + threadIdx.x; i < n8;
         i += (size_t)gridDim.x * blockDim.x) {
        size_t base = i * 8;
        const float* src;
        if (base < S0)                src = f0 + base;
        else if (base < S0 + S1)      src = f1 + (base - S0);
        else if (base < S0 + S1 + S2) src = f2 + (base - S0 - S1);
        else                          src = f3 + (base - S0 - S1 - S2);

        float4 a = *(const float4*)(src);
        float4 b = *(const float4*)(src + 4);
        uint4 o;
        o.x = (unsigned int)f2b(a.x) | ((unsigned int)f2b(a.y) << 16);
        o.y = (unsigned int)f2b(a.z) | ((unsigned int)f2b(a.w) << 16);
        o.z = (unsigned int)f2b(b.x) | ((unsigned int)f2b(b.y) << 16);
        o.w = (unsigned int)f2b(b.z) | ((unsigned int)f2b(b.w) << 16);
        *(uint4*)(out + base) = o;
    }
}

// ---------------- prepass 2: per-sample metadata ----------------
// For each (a, pc, level): 4 corner BYTE offsets into fmw, 4 geometric
// bilinear weights (zeroed for out-of-bounds corners).
__global__ __launch_bounds__(256) void meta_kernel(
    const float* __restrict__ pts,
    int4* __restrict__ mi, float4* __restrict__ mw)
{
    const int t = blockIdx.x * 256 + threadIdx.x;
    if (t >= N_SAMP) return;
    const int a     = t / (N_PC * N_LVL);
    const int r     = t - a * (N_PC * N_LVL);
    const int pc    = r >> 2;
    const int level = r & 3;
    const int cam   = pc % N_CAM;

    const int Hs[4] = {64, 32, 16, 8};
    const int Ws[4] = {176, 88, 44, 22};
    const int Bs[4] = {PB0, PB1, PB2, PB3};   // pixel-unit segment bases
    const int H = Hs[level], W = Ws[level], lb = Bs[level];
    const int HW = H * W;

    const float2 pt = ((const float2*)pts)[a * N_PC + pc];
    float x = pt.x * (float)W - 0.5f;
    float y = pt.y * (float)H - 0.5f;
    float x0f = floorf(x), y0f = floorf(y);
    int   x0 = (int)x0f,  y0 = (int)y0f;
    float wx1 = x - x0f,  wy1 = y - y0f;
    float wx0 = 1.f - wx1, wy0 = 1.f - wy1;
    if (x0 < 0 || x0 >= W)         wx0 = 0.f;
    if (x0 + 1 < 0 || x0 + 1 >= W) wx1 = 0.f;
    if (y0 < 0 || y0 >= H)         wy0 = 0.f;
    if (y0 + 1 < 0 || y0 + 1 >= H) wy1 = 0.f;

    int xc0 = min(max(x0, 0), W - 1);
    int xc1 = min(max(x0 + 1, 0), W - 1);
    int yc0 = min(max(y0, 0), H - 1);
    int yc1 = min(max(y0 + 1, 0), H - 1);

    const int base = lb + cam * HW;           // pixel index
    // byte offsets: pixel * 256 ch * 2 B
    int4 off;
    off.x = (base + yc0 * W + xc0) * (C_CH * 2);
    off.y = (base + yc0 * W + xc1) * (C_CH * 2);
    off.z = (base + yc1 * W + xc0) * (C_CH * 2);
    off.w = (base + yc1 * W + xc1) * (C_CH * 2);
    mi[t] = off;
    mw[t] = make_float4(wx0 * wy0, wx1 * wy0, wx0 * wy1, wx1 * wy1);
}

// ---------------- gather: bf16 fm -> acc[900][256] (fp32, in ws) ----------------
__global__ __launch_bounds__(1024, 8) void daf_gather_meta(
    const unsigned short* __restrict__ fmw,
    const int4* __restrict__ mi, const float4* __restrict__ mw,
    const float* __restrict__ wts,
    float* __restrict__ acc_out)
{
    const int a    = blockIdx.x;
    const int tid  = threadIdx.x;
    const int wv   = tid >> 6;          // 0..15
    const int lane = tid & 63;
    const int level = wv & 3;
    const int chunk = wv >> 2;          // 0..3

    const int c0  = lane << 2;          // channel (element) base
    const int c0b = lane << 3;          // channel byte offset (4 bf16 = 8 B)
    const int g   = lane >> 3;

    const int4*   __restrict__ mi_a = mi + (size_t)a * (N_PC * N_LVL);
    const float4* __restrict__ mw_a = mw + (size_t)a * (N_PC * N_LVL);
    const float*  __restrict__ wts_a = wts + (size_t)a * (N_PC * N_LVL * N_GRP);
    const char*   __restrict__ fmb = (const char*)fmw;

    const int start = chunk * 20;
    const int end   = (chunk == 3) ? N_PC : (start + 20);

    float4 acc = make_float4(0.f, 0.f, 0.f, 0.f);

#pragma unroll 2
    for (int pc = start; pc < end; ++pc) {
        const int s = pc * N_LVL + level;
        const int4   off = mi_a[s];
        const float4 gw  = mw_a[s];
        const float  wg  = wts_a[pc * (N_LVL * N_GRP) + level * N_GRP + g];

        const uint2 u00 = *(const uint2*)(fmb + (unsigned)(off.x + c0b));
        const uint2 u10 = *(const uint2*)(fmb + (unsigned)(off.y + c0b));
        const uint2 u01 = *(const uint2*)(fmb + (unsigned)(off.z + c0b));
        const uint2 u11 = *(const uint2*)(fmb + (unsigned)(off.w + c0b));

        const float w00 = gw.x * wg, w10 = gw.y * wg;
        const float w01 = gw.z * wg, w11 = gw.w * wg;

        acc.x = fmaf(bflo(u00.x), w00, acc.x);
        acc.y = fmaf(bfhi(u00.x), w00, acc.y);
        acc.z = fmaf(bflo(u00.y), w00, acc.z);
        acc.w = fmaf(bfhi(u00.y), w00, acc.w);
        acc.x = fmaf(bflo(u10.x), w10, acc.x);
        acc.y = fmaf(bfhi(u10.x), w10, acc.y);
        acc.z = fmaf(bflo(u10.y), w10, acc.z);
        acc.w = fmaf(bfhi(u10.y), w10, acc.w);
        acc.x = fmaf(bflo(u01.x), w01, acc.x);
        acc.y = fmaf(bfhi(u01.x), w01, acc.y);
        acc.z = fmaf(bflo(u01.y), w01, acc.z);
        acc.w = fmaf(bfhi(u01.y), w01, acc.w);
        acc.x = fmaf(bflo(u11.x), w11, acc.x);
        acc.y = fmaf(bfhi(u11.x), w11, acc.y);
        acc.z = fmaf(bflo(u11.y), w11, acc.z);
        acc.w = fmaf(bfhi(u11.y), w11, acc.w);
    }

    __shared__ float s_part[16][C_CH];
    *(float4*)&s_part[wv][c0] = acc;
    __syncthreads();

    if (tid < C_CH) {
        float t = 0.f;
#pragma unroll
        for (int i = 0; i < 16; ++i) t += s_part[i][tid];
        acc_out[(size_t)a * C_CH + tid] = t;
    }
}

// ---------------- proj: out = acc @ wproj + b, concat inst ----------------
// grid (113 m-tiles, 4 j-tiles), block 256 = 4 waves; wave mg handles 2 anchors.
__global__ __launch_bounds__(256) void daf_proj_kernel(
    const float* __restrict__ accb, const float* __restrict__ wproj,
    const float* __restrict__ bproj, const float* __restrict__ inst,
    float* __restrict__ out)
{
    const int m0 = blockIdx.x * TM;
    const int jt = blockIdx.y;
    const int tid = threadIdx.x;
    const int j  = jt * 64 + (tid & 63);
    const int mg = tid >> 6;             // 0..3
    const int ma = m0 + mg * 2;
    const int mb = ma + 1;
    const int nvalid = min(TM, A_TOT - m0);

    __shared__ float s_acc[TM][C_CH];    // 8 KB

    // cooperative load: TM*256 floats = 512 float4s, 256 threads -> 2 each
#pragma unroll
    for (int q = 0; q < (TM * C_CH / 4); q += 256) {
        int f4 = q + tid;
        int m  = f4 >> 6;
        int c  = (f4 & 63) << 2;
        float4 v = (m < nvalid)
            ? *(const float4*)(accb + (size_t)(m0 + m) * C_CH + c)
            : make_float4(0.f, 0.f, 0.f, 0.f);
        *(float4*)&s_acc[m][c] = v;
    }
    __syncthreads();

    float ra = 0.f, rb = 0.f;
    const int la = mg * 2, lb2 = la + 1;
    for (int kb = 0; kb < C_CH; kb += 4) {
        float w0 = wproj[(size_t)(kb + 0) * C_CH + j];
        float w1 = wproj[(size_t)(kb + 1) * C_CH + j];
        float w2 = wproj[(size_t)(kb + 2) * C_CH + j];
        float w3 = wproj[(size_t)(kb + 3) * C_CH + j];
        float4 a4 = *(const float4*)&s_acc[la][kb];
        float4 b4 = *(const float4*)&s_acc[lb2][kb];
        ra = fmaf(a4.x, w0, ra); ra = fmaf(a4.y, w1, ra);
        ra = fmaf(a4.z, w2, ra); ra = fmaf(a4.w, w3, ra);
        rb = fmaf(b4.x, w0, rb); rb = fmaf(b4.y, w1, rb);
        rb = fmaf(b4.z, w2, rb); rb = fmaf(b4.w, w3, rb);
    }

    const float b = bproj[j];
    if (ma < A_TOT) {
        out[(size_t)ma * 512 + j]         = ra + b;
        out[(size_t)ma * 512 + C_CH + j]  = inst[(size_t)ma * C_CH + j];
    }
    if (mb < A_TOT) {
        out[(size_t)mb * 512 + j]         = rb + b;
        out[(size_t)mb * 512 + C_CH + j]  = inst[(size_t)mb * C_CH + j];
    }
}

// ---------------- mid fallback: r4 fused bf16 (needs only FMW_BYTES) ----------------
__global__ __launch_bounds__(1024, 8) void daf_fused_bf16(
    const unsigned short* __restrict__ fmw,
    const float* __restrict__ pts, const float* __restrict__ wts,
    const float* __restrict__ inst, const float* __restrict__ wproj,
    const float* __restrict__ bproj, float* __restrict__ out)
{
    const int a    = blockIdx.x;
    const int tid  = threadIdx.x;
    const int wv   = tid >> 6;
    const int lane = tid & 63;
    const int level = wv & 3;
    const int chunk = wv >> 2;

    const unsigned short* fm; int H, W;
    if (level == 0)      { fm = fmw;                 H = 64; W = 176; }
    else if (level == 1) { fm = fmw + S0;            H = 32; W = 88;  }
    else if (level == 2) { fm = fmw + S0 + S1;       H = 16; W = 44;  }
    else                 { fm = fmw + S0 + S1 + S2;  H = 8;  W = 22;  }
    const float fW = (float)W, fH = (float)H;
    const int HW = H * W;

    const int c0 = lane << 2;
    const int g  = lane >> 3;

    const float2* __restrict__ pts_a = (const float2*)(pts + (size_t)a * (N_PC * 2));
    const float*  __restrict__ wts_a = wts + (size_t)a * (N_PC * N_LVL * N_GRP);

    const int start = chunk * 20;
    const int end   = (chunk == 3) ? N_PC : (start + 20);

    float4 acc = make_float4(0.f, 0.f, 0.f, 0.f);

#pragma unroll 2
    for (int pc = start; pc < end; ++pc) {
        const int cam = pc % N_CAM;
        float2 pt = pts_a[pc];
        float x = pt.x * fW - 0.5f;
        float y = pt.y * fH - 0.5f;
        float x0f = floorf(x), y0f = floorf(y);
        int   x0 = (int)x0f,  y0 = (int)y0f;
        float wx1 = x - x0f,  wy1 = y - y0f;
        float wx0 = 1.f - wx1, wy0 = 1.f - wy1;
        if (x0 < 0 || x0 >= W)         wx0 = 0.f;
        if (x0 + 1 < 0 || x0 + 1 >= W) wx1 = 0.f;
        if (y0 < 0 || y0 >= H)         wy0 = 0.f;
        if (y0 + 1 < 0 || y0 + 1 >= H) wy1 = 0.f;

        float w = wts_a[pc * (N_LVL * N_GRP) + level * N_GRP + g];
        wx0 *= w; wx1 *= w;

        int xc0 = min(max(x0, 0), W - 1);
        int xc1 = min(max(x0 + 1, 0), W - 1);
        int yc0 = min(max(y0, 0), H - 1);
        int yc1 = min(max(y0 + 1, 0), H - 1);

        const int base = cam * HW;
        const int r0 = base + yc0 * W;
        const int r1 = base + yc1 * W;

        ushort4 u00 = *(const ushort4*)(fm + (size_t)(r0 + xc0) * C_CH + c0);
        ushort4 u10 = *(const ushort4*)(fm + (size_t)(r0 + xc1) * C_CH + c0);
        ushort4 u01 = *(const ushort4*)(fm + (size_t)(r1 + xc0) * C_CH + c0);
        ushort4 u11 = *(const ushort4*)(fm + (size_t)(r1 + xc1) * C_CH + c0);

        float w00 = wx0 * wy0, w10 = wx1 * wy0;
        float w01 = wx0 * wy1, w11 = wx1 * wy1;

        acc.x = fmaf(bf2f(u00.x), w00, acc.x);
        acc.y = fmaf(bf2f(u00.y), w00, acc.y);
        acc.z = fmaf(bf2f(u00.z), w00, acc.z);
        acc.w = fmaf(bf2f(u00.w), w00, acc.w);
        acc.x = fmaf(bf2f(u10.x), w10, acc.x);
        acc.y = fmaf(bf2f(u10.y), w10, acc.y);
        acc.z = fmaf(bf2f(u10.z), w10, acc.z);
        acc.w = fmaf(bf2f(u10.w), w10, acc.w);
        acc.x = fmaf(bf2f(u01.x), w01, acc.x);
        acc.y = fmaf(bf2f(u01.y), w01, acc.y);
        acc.z = fmaf(bf2f(u01.z), w01, acc.z);
        acc.w = fmaf(bf2f(u01.w), w01, acc.w);
        acc.x = fmaf(bf2f(u11.x), w11, acc.x);
        acc.y = fmaf(bf2f(u11.y), w11, acc.y);
        acc.z = fmaf(bf2f(u11.z), w11, acc.z);
        acc.w = fmaf(bf2f(u11.w), w11, acc.w);
    }

    __shared__ float s_part[16][C_CH];
    __shared__ float s_tot[C_CH];
    __shared__ float s_proj[4][C_CH];

    *(float4*)&s_part[wv][c0] = acc;
    __syncthreads();

    if (tid < C_CH) {
        float t = 0.f;
#pragma unroll
        for (int i = 0; i < 16; ++i) t += s_part[i][tid];
        s_tot[tid] = t;
    }
    __syncthreads();

    {
        const int j = tid & (C_CH - 1);
        const int q = tid >> 8;
        const int kb = q * 64;
        float r0s = 0.f, r1s = 0.f, r2s = 0.f, r3s = 0.f;
#pragma unroll 4
        for (int k = kb; k < kb + 64; k += 4) {
            r0s = fmaf(s_tot[k + 0], wproj[(size_t)(k + 0) * C_CH + j], r0s);
            r1s = fmaf(s_tot[k + 1], wproj[(size_t)(k + 1) * C_CH + j], r1s);
            r2s = fmaf(s_tot[k + 2], wproj[(size_t)(k + 2) * C_CH + j], r2s);
            r3s = fmaf(s_tot[k + 3], wproj[(size_t)(k + 3) * C_CH + j], r3s);
        }
        s_proj[q][j] = (r0s + r1s) + (r2s + r3s);
    }
    __syncthreads();

    if (tid < C_CH) {
        float r = (s_proj[0][tid] + s_proj[1][tid]) + (s_proj[2][tid] + s_proj[3][tid])
                  + bproj[tid];
        out[(size_t)a * 512 + tid] = r;
    } else if (tid < 2 * C_CH) {
        const int j = tid - C_CH;
        out[(size_t)a * 512 + C_CH + j] = inst[(size_t)a * C_CH + j];
    }
}

// ---------------- last fallback: fp32 fused ----------------
__global__ __launch_bounds__(1024, 8) void daf_fused_fp32(
    const float* __restrict__ fm0, const float* __restrict__ fm1,
    const float* __restrict__ fm2, const float* __restrict__ fm3,
    const float* __restrict__ pts, const float* __restrict__ wts,
    const float* __restrict__ inst, const float* __restrict__ wproj,
    const float* __restrict__ bproj, float* __restrict__ out)
{
    const int a    = blockIdx.x;
    const int tid  = threadIdx.x;
    const int wv   = tid >> 6;
    const int lane = tid & 63;
    const int level = wv & 3;
    const int chunk = wv >> 2;

    const float* fm; int H, W;
    if (level == 0)      { fm = fm0; H = 64; W = 176; }
    else if (level == 1) { fm = fm1; H = 32; W = 88;  }
    else if (level == 2) { fm = fm2; H = 16; W = 44;  }
    else                 { fm = fm3; H = 8;  W = 22;  }
    const float fW = (float)W, fH = (float)H;
    const int HW = H * W;

    const int c0 = lane << 2;
    const int g  = lane >> 3;

    const float2* __restrict__ pts_a = (const float2*)(pts + (size_t)a * (N_PC * 2));
    const float*  __restrict__ wts_a = wts + (size_t)a * (N_PC * N_LVL * N_GRP);

    const int start = chunk * 20;
    const int end   = (chunk == 3) ? N_PC : (start + 20);

    float4 acc = make_float4(0.f, 0.f, 0.f, 0.f);

#pragma unroll 2
    for (int pc = start; pc < end; ++pc) {
        const int cam = pc % N_CAM;
        float2 pt = pts_a[pc];
        float x = pt.x * fW - 0.5f;
        float y = pt.y * fH - 0.5f;
        float x0f = floorf(x), y0f = floorf(y);
        int   x0 = (int)x0f,  y0 = (int)y0f;
        float wx1 = x - x0f,  wy1 = y - y0f;
        float wx0 = 1.f - wx1, wy0 = 1.f - wy1;
        if (x0 < 0 || x0 >= W)         wx0 = 0.f;
        if (x0 + 1 < 0 || x0 + 1 >= W) wx1 = 0.f;
        if (y0 < 0 || y0 >= H)         wy0 = 0.f;
        if (y0 + 1 < 0 || y0 + 1 >= H) wy1 = 0.f;

        float w = wts_a[pc * (N_LVL * N_GRP) + level * N_GRP + g];
        wx0 *= w; wx1 *= w;

        int xc0 = min(max(x0, 0), W - 1);
        int xc1 = min(max(x0 + 1, 0), W - 1);
        int yc0 = min(max(y0, 0), H - 1);
        int yc1 = min(max(y0 + 1, 0), H - 1);

        const int base = cam * HW;
        const int r0 = base + yc0 * W;
        const int r1 = base + yc1 * W;

        float4 v00 = *(const float4*)(fm + (size_t)(r0 + xc0) * C_CH + c0);
        float4 v10 = *(const float4*)(fm + (size_t)(r0 + xc1) * C_CH + c0);
        float4 v01 = *(const float4*)(fm + (size_t)(r1 + xc0) * C_CH + c0);
        float4 v11 = *(const float4*)(fm + (size_t)(r1 + xc1) * C_CH + c0);

        float w00 = wx0 * wy0, w10 = wx1 * wy0;
        float w01 = wx0 * wy1, w11 = wx1 * wy1;

        acc.x = fmaf(v00.x, w00, acc.x);
        acc.y = fmaf(v00.y, w00, acc.y);
        acc.z = fmaf(v00.z, w00, acc.z);
        acc.w = fmaf(v00.w, w00, acc.w);
        acc.x = fmaf(v10.x, w10, acc.x);
        acc.y = fmaf(v10.y, w10, acc.y);
        acc.z = fmaf(v10.z, w10, acc.z);
        acc.w = fmaf(v10.w, w10, acc.w);
        acc.x = fmaf(v01.x, w01, acc.x);
        acc.y = fmaf(v01.y, w01, acc.y);
        acc.z = fmaf(v01.z, w01, acc.z);
        acc.w = fmaf(v01.w, w01, acc.w);
        acc.x = fmaf(v11.x, w11, acc.x);
        acc.y = fmaf(v11.y, w11, acc.y);
        acc.z = fmaf(v11.z, w11, acc.z);
        acc.w = fmaf(v11.w, w11, acc.w);
    }

    __shared__ float s_part[16][C_CH];
    __shared__ float s_tot[C_CH];
    __shared__ float s_proj[4][C_CH];

    *(float4*)&s_part[wv][c0] = acc;
    __syncthreads();

    if (tid < C_CH) {
        float t = 0.f;
#pragma unroll
        for (int i = 0; i < 16; ++i) t += s_part[i][tid];
        s_tot[tid] = t;
    }
    __syncthreads();

    {
        const int j = tid & (C_CH - 1);
        const int q = tid >> 8;
        const int kb = q * 64;
        float r0s = 0.f, r1s = 0.f, r2s = 0.f, r3s = 0.f;
#pragma unroll 4
        for (int k = kb; k < kb + 64; k += 4) {
            r0s = fmaf(s_tot[k + 0], wproj[(size_t)(k + 0) * C_CH + j], r0s);
            r1s = fmaf(s_tot[k + 1], wproj[(size_t)(k + 1) * C_CH + j], r1s);
            r2s = fmaf(s_tot[k + 2], wproj[(size_t)(k + 2) * C_CH + j], r2s);
            r3s = fmaf(s_tot[k + 3], wproj[(size_t)(k + 3) * C_CH + j], r3s);
        }
        s_proj[q][j] = (r0s + r1s) + (r2s + r3s);
    }
    __syncthreads();

    if (tid < C_CH) {
        float r = (s_proj[0][tid] + s_proj[1][tid]) + (s_proj[2][tid] + s_proj[3][tid])
                  + bproj[tid];
        out[(size_t)a * 512 + tid] = r;
    } else if (tid < 2 * C_CH) {
        const int j = tid - C_CH;
        out[(size_t)a * 512 + C_CH + j] = inst[(size_t)a * C_CH + j];
    }
}

extern "C" void kernel_launch(void* const* d_in, const int* in_sizes, int n_in,
                              void* d_out, int out_size, void* d_ws, size_t ws_size,
                              hipStream_t stream) {
    const float* fm0   = (const float*)d_in[0];
    const float* fm1   = (const float*)d_in[1];
    const float* fm2   = (const float*)d_in[2];
    const float* fm3   = (const float*)d_in[3];
    const float* pts   = (const float*)d_in[4];
    const float* wts   = (const float*)d_in[5];
    const float* inst  = (const float*)d_in[6];
    const float* wproj = (const float*)d_in[7];
    const float* bproj = (const float*)d_in[8];
    float* out = (float*)d_out;

    if (ws_size >= WS_FULL) {
        unsigned short* fmw = (unsigned short*)d_ws;
        float* accb = (float*)((char*)d_ws + FMW_BYTES);
        int4*   mi  = (int4*)((char*)d_ws + FMW_BYTES + ACC_BYTES);
        float4* mw  = (float4*)((char*)d_ws + FMW_BYTES + ACC_BYTES + METAI_BYTES);

        convert_bf16_kernel<<<2048, 256, 0, stream>>>(fm0, fm1, fm2, fm3, fmw);
        meta_kernel<<<(N_SAMP + 255) / 256, 256, 0, stream>>>(pts, mi, mw);
        daf_gather_meta<<<A_TOT, 1024, 0, stream>>>(fmw, mi, mw, wts, accb);
        dim3 pg((A_TOT + TM - 1) / TM, 4);
        daf_proj_kernel<<<pg, 256, 0, stream>>>(accb, wproj, bproj, inst, out);
    } else if (ws_size >= WS_MID) {
        unsigned short* fmw = (unsigned short*)d_ws;
        convert_bf16_kernel<<<2048, 256, 0, stream>>>(fm0, fm1, fm2, fm3, fmw);
        daf_fused_bf16<<<A_TOT, 1024, 0, stream>>>(
            fmw, pts, wts, inst, wproj, bproj, out);
    } else {
        daf_fused_fp32<<<A_TOT, 1024, 0, stream>>>(
            fm0, fm1, fm2, fm3, pts, wts, inst, wproj, bproj, out);
    }
}

// Round 8
// 92.850 us; speedup vs baseline: 1.0848x; 1.0848x over previous
//
#include <hip/hip_runtime.h>
#include <hip/hip_bf16.h>

// Sparse4DHead1st deformable aggregation + output_proj + concat.
// Inputs (fp32): fm0..fm3, points_2d, weights, instance_feature, w_proj, b_proj
// Output (fp32): [1, 900, 512] = concat(acc @ w_proj + b, instance_feature)
//
// Round 8: pair-load gather. The two x-corners of a bilinear row are 1KB
// contiguous -> one dwordx4 load per row covers both (lanes 0-31 = pixel
// xb, lanes 32-63 = pixel xb+1). 2 loads/sample instead of 4. Setup stays
// in-kernel (r7 showed meta-table loads create a latency chain; VALU setup
// overlaps under memory). Separate 452-block proj; bf16 convert prepass.

#define A_TOT 900
#define P_PTS 13
#define N_CAM 6
#define C_CH  256
#define N_GRP 8
#define N_LVL 4
#define N_PC  (P_PTS * N_CAM)    // 78

// bf16 fm segment sizes (elements)
#define S0 17301504   // 6*64*176*256
#define S1 4325376    // 6*32*88*256
#define S2 1081344    // 6*16*44*256
#define S3 270336     // 6*8*22*256
#define S_TOT (S0 + S1 + S2 + S3)            // 22,978,560 elts
// segment bases in PIXELS (element base / 256)
#define PB0 0
#define PB1 67584     // S0/256
#define PB2 84480     // (S0+S1)/256
#define PB3 88704     // (S0+S1+S2)/256
#define FMW_BYTES ((size_t)S_TOT * 2)        // 45,957,120
#define ACC_BYTES ((size_t)A_TOT * C_CH * 4) //    921,600
#define WS_MID  (FMW_BYTES)
#define WS_FULL (FMW_BYTES + ACC_BYTES)      // 46,878,720

#define TM 8   // anchors per proj m-tile

__device__ __forceinline__ float bf2f(unsigned short u) {
    unsigned int t = ((unsigned int)u) << 16;
    float f;
    __builtin_memcpy(&f, &t, 4);
    return f;
}
__device__ __forceinline__ float bflo(unsigned int u) {   // low bf16 of packed u32
    unsigned int t = u << 16; float f; __builtin_memcpy(&f, &t, 4); return f;
}
__device__ __forceinline__ float bfhi(unsigned int u) {   // high bf16 of packed u32
    unsigned int t = u & 0xffff0000u; float f; __builtin_memcpy(&f, &t, 4); return f;
}
__device__ __forceinline__ unsigned short f2b(float x) {
    __hip_bfloat16 h = __float2bfloat16(x);   // RNE
    unsigned short b;
    __builtin_memcpy(&b, &h, 2);
    return b;
}

// ---------------- prepass: fp32 -> bf16 ----------------
__global__ __launch_bounds__(256) void convert_bf16_kernel(
    const float* __restrict__ f0, const float* __restrict__ f1,
    const float* __restrict__ f2, const float* __restrict__ f3,
    unsigned short* __restrict__ out)
{
    const size_t n8 = S_TOT / 8;
    for (size_t i = (size_t)blockIdx.x * blockDim.x + threadIdx.x; i < n8;
         i += (size_t)gridDim.x * blockDim.x) {
        size_t base = i * 8;
        const float* src;
        if (base < S0)                src = f0 + base;
        else if (base < S0 + S1)      src = f1 + (base - S0);
        else if (base < S0 + S1 + S2) src = f2 + (base - S0 - S1);
        else                          src = f3 + (base - S0 - S1 - S2);

        float4 a = *(const float4*)(src);
        float4 b = *(const float4*)(src + 4);
        uint4 o;
        o.x = (unsigned int)f2b(a.x) | ((unsigned int)f2b(a.y) << 16);
        o.y = (unsigned int)f2b(a.z) | ((unsigned int)f2b(a.w) << 16);
        o.z = (unsigned int)f2b(b.x) | ((unsigned int)f2b(b.y) << 16);
        o.w = (unsigned int)f2b(b.z) | ((unsigned int)f2b(b.w) << 16);
        *(uint4*)(out + base) = o;
    }
}

// ---------------- gather (pair loads): bf16 fm -> acc[900][256] ----------------
__global__ __launch_bounds__(1024, 8) void daf_gather_pair(
    const unsigned short* __restrict__ fmw,
    const float* __restrict__ pts, const float* __restrict__ wts,
    float* __restrict__ acc_out)
{
    const int a    = blockIdx.x;
    const int tid  = threadIdx.x;
    const int wv   = tid >> 6;          // 0..15
    const int lane = tid & 63;
    const int level = wv & 3;
    const int chunk = wv >> 2;          // 0..3

    int H, W, pb;
    if (level == 0)      { H = 64; W = 176; pb = PB0; }
    else if (level == 1) { H = 32; W = 88;  pb = PB1; }
    else if (level == 2) { H = 16; W = 44;  pb = PB2; }
    else                 { H = 8;  W = 22;  pb = PB3; }
    const float fW = (float)W, fH = (float)H;
    const int HW = H * W;

    const int lh = lane >> 5;           // x-half: 0 -> pixel xb, 1 -> xb+1
    const int l5 = lane & 31;           // channel block: c0 = l5*8
    const int g  = l5 >> 2;             // group = (l5*8)/32
    const int cbyte = lane << 4;        // byte offset within the 1KB pair

    const float2* __restrict__ pts_a = (const float2*)(pts + (size_t)a * (N_PC * 2));
    const float*  __restrict__ wts_a = wts + (size_t)a * (N_PC * N_LVL * N_GRP);
    const char*   __restrict__ fmb = (const char*)fmw;

    const int start = chunk * 20;
    const int end   = (chunk == 3) ? N_PC : (start + 20);

    float acc[8];
#pragma unroll
    for (int i = 0; i < 8; ++i) acc[i] = 0.f;

#pragma unroll 2
    for (int pc = start; pc < end; ++pc) {
        const int cam = pc % N_CAM;
        float2 pt = pts_a[pc];
        float x = pt.x * fW - 0.5f;
        float y = pt.y * fH - 0.5f;
        float x0f = floorf(x), y0f = floorf(y);
        int   x0 = (int)x0f,  y0 = (int)y0f;
        float wx1 = x - x0f,  wy1 = y - y0f;
        float wx0 = 1.f - wx1, wy0 = 1.f - wy1;
        // zero-padding masks
        if (x0 < 0 || x0 >= W)         wx0 = 0.f;
        if (x0 + 1 < 0 || x0 + 1 >= W) wx1 = 0.f;
        if (y0 < 0 || y0 >= H)         wy0 = 0.f;
        if (y0 + 1 < 0 || y0 + 1 >= H) wy1 = 0.f;

        // x pair base and per-half weights (handles x0=-1 and x0=W-1)
        const int xb = min(max(x0, 0), W - 2);
        float wA = ((xb == x0) ? wx0 : 0.f) + ((xb == x0 + 1) ? wx1 : 0.f);
        float wB = ((xb + 1 == x0) ? wx0 : 0.f) + ((xb + 1 == x0 + 1) ? wx1 : 0.f);

        const int yc0 = min(max(y0, 0), H - 1);
        const int yc1 = min(max(y0 + 1, 0), H - 1);

        const float wg  = wts_a[pc * (N_LVL * N_GRP) + level * N_GRP + g];
        const float wxh = lh ? wB : wA;
        const float wr0 = wxh * wy0 * wg;
        const float wr1 = wxh * wy1 * wg;

        const int rowbase = pb + cam * HW + xb;
        const int off0 = (rowbase + yc0 * W) * (C_CH * 2) + cbyte;
        const int off1 = (rowbase + yc1 * W) * (C_CH * 2) + cbyte;

        const uint4 rA = *(const uint4*)(fmb + off0);
        const uint4 rB = *(const uint4*)(fmb + off1);

        acc[0] = fmaf(bflo(rA.x), wr0, acc[0]);
        acc[1] = fmaf(bfhi(rA.x), wr0, acc[1]);
        acc[2] = fmaf(bflo(rA.y), wr0, acc[2]);
        acc[3] = fmaf(bfhi(rA.y), wr0, acc[3]);
        acc[4] = fmaf(bflo(rA.z), wr0, acc[4]);
        acc[5] = fmaf(bfhi(rA.z), wr0, acc[5]);
        acc[6] = fmaf(bflo(rA.w), wr0, acc[6]);
        acc[7] = fmaf(bfhi(rA.w), wr0, acc[7]);

        acc[0] = fmaf(bflo(rB.x), wr1, acc[0]);
        acc[1] = fmaf(bfhi(rB.x), wr1, acc[1]);
        acc[2] = fmaf(bflo(rB.y), wr1, acc[2]);
        acc[3] = fmaf(bfhi(rB.y), wr1, acc[3]);
        acc[4] = fmaf(bflo(rB.z), wr1, acc[4]);
        acc[5] = fmaf(bfhi(rB.z), wr1, acc[5]);
        acc[6] = fmaf(bflo(rB.w), wr1, acc[6]);
        acc[7] = fmaf(bfhi(rB.w), wr1, acc[7]);
    }

    // combine x-halves: lane L and L+32 hold the two pixels' partials for
    // the same 8 channels
#pragma unroll
    for (int i = 0; i < 8; ++i) acc[i] += __shfl_xor(acc[i], 32);

    __shared__ float s_part[16][C_CH];
    // all 64 lanes write; L and L+32 write identical values to the same
    // address (benign)
    {
        float4 v0 = make_float4(acc[0], acc[1], acc[2], acc[3]);
        float4 v1 = make_float4(acc[4], acc[5], acc[6], acc[7]);
        *(float4*)&s_part[wv][l5 * 8]     = v0;
        *(float4*)&s_part[wv][l5 * 8 + 4] = v1;
    }
    __syncthreads();

    if (tid < C_CH) {
        float t = 0.f;
#pragma unroll
        for (int i = 0; i < 16; ++i) t += s_part[i][tid];
        acc_out[(size_t)a * C_CH + tid] = t;
    }
}

// ---------------- proj: out = acc @ wproj + b, concat inst ----------------
// grid (113 m-tiles, 4 j-tiles), block 256 = 4 waves; wave mg handles 2 anchors.
__global__ __launch_bounds__(256) void daf_proj_kernel(
    const float* __restrict__ accb, const float* __restrict__ wproj,
    const float* __restrict__ bproj, const float* __restrict__ inst,
    float* __restrict__ out)
{
    const int m0 = blockIdx.x * TM;
    const int jt = blockIdx.y;
    const int tid = threadIdx.x;
    const int j  = jt * 64 + (tid & 63);
    const int mg = tid >> 6;             // 0..3
    const int ma = m0 + mg * 2;
    const int mb = ma + 1;
    const int nvalid = min(TM, A_TOT - m0);

    __shared__ float s_acc[TM][C_CH];    // 8 KB

#pragma unroll
    for (int q = 0; q < (TM * C_CH / 4); q += 256) {
        int f4 = q + tid;
        int m  = f4 >> 6;
        int c  = (f4 & 63) << 2;
        float4 v = (m < nvalid)
            ? *(const float4*)(accb + (size_t)(m0 + m) * C_CH + c)
            : make_float4(0.f, 0.f, 0.f, 0.f);
        *(float4*)&s_acc[m][c] = v;
    }
    __syncthreads();

    float ra = 0.f, rb = 0.f;
    const int la = mg * 2, lb2 = la + 1;
    for (int kb = 0; kb < C_CH; kb += 4) {
        float w0 = wproj[(size_t)(kb + 0) * C_CH + j];
        float w1 = wproj[(size_t)(kb + 1) * C_CH + j];
        float w2 = wproj[(size_t)(kb + 2) * C_CH + j];
        float w3 = wproj[(size_t)(kb + 3) * C_CH + j];
        float4 a4 = *(const float4*)&s_acc[la][kb];
        float4 b4 = *(const float4*)&s_acc[lb2][kb];
        ra = fmaf(a4.x, w0, ra); ra = fmaf(a4.y, w1, ra);
        ra = fmaf(a4.z, w2, ra); ra = fmaf(a4.w, w3, ra);
        rb = fmaf(b4.x, w0, rb); rb = fmaf(b4.y, w1, rb);
        rb = fmaf(b4.z, w2, rb); rb = fmaf(b4.w, w3, rb);
    }

    const float b = bproj[j];
    if (ma < A_TOT) {
        out[(size_t)ma * 512 + j]         = ra + b;
        out[(size_t)ma * 512 + C_CH + j]  = inst[(size_t)ma * C_CH + j];
    }
    if (mb < A_TOT) {
        out[(size_t)mb * 512 + j]         = rb + b;
        out[(size_t)mb * 512 + C_CH + j]  = inst[(size_t)mb * C_CH + j];
    }
}

// ---------------- mid fallback: r4 fused bf16 (needs only FMW_BYTES) ----------------
__global__ __launch_bounds__(1024, 8) void daf_fused_bf16(
    const unsigned short* __restrict__ fmw,
    const float* __restrict__ pts, const float* __restrict__ wts,
    const float* __restrict__ inst, const float* __restrict__ wproj,
    const float* __restrict__ bproj, float* __restrict__ out)
{
    const int a    = blockIdx.x;
    const int tid  = threadIdx.x;
    const int wv   = tid >> 6;
    const int lane = tid & 63;
    const int level = wv & 3;
    const int chunk = wv >> 2;

    const unsigned short* fm; int H, W;
    if (level == 0)      { fm = fmw;                 H = 64; W = 176; }
    else if (level == 1) { fm = fmw + S0;            H = 32; W = 88;  }
    else if (level == 2) { fm = fmw + S0 + S1;       H = 16; W = 44;  }
    else                 { fm = fmw + S0 + S1 + S2;  H = 8;  W = 22;  }
    const float fW = (float)W, fH = (float)H;
    const int HW = H * W;

    const int c0 = lane << 2;
    const int g  = lane >> 3;

    const float2* __restrict__ pts_a = (const float2*)(pts + (size_t)a * (N_PC * 2));
    const float*  __restrict__ wts_a = wts + (size_t)a * (N_PC * N_LVL * N_GRP);

    const int start = chunk * 20;
    const int end   = (chunk == 3) ? N_PC : (start + 20);

    float4 acc = make_float4(0.f, 0.f, 0.f, 0.f);

#pragma unroll 2
    for (int pc = start; pc < end; ++pc) {
        const int cam = pc % N_CAM;
        float2 pt = pts_a[pc];
        float x = pt.x * fW - 0.5f;
        float y = pt.y * fH - 0.5f;
        float x0f = floorf(x), y0f = floorf(y);
        int   x0 = (int)x0f,  y0 = (int)y0f;
        float wx1 = x - x0f,  wy1 = y - y0f;
        float wx0 = 1.f - wx1, wy0 = 1.f - wy1;
        if (x0 < 0 || x0 >= W)         wx0 = 0.f;
        if (x0 + 1 < 0 || x0 + 1 >= W) wx1 = 0.f;
        if (y0 < 0 || y0 >= H)         wy0 = 0.f;
        if (y0 + 1 < 0 || y0 + 1 >= H) wy1 = 0.f;

        float w = wts_a[pc * (N_LVL * N_GRP) + level * N_GRP + g];
        wx0 *= w; wx1 *= w;

        int xc0 = min(max(x0, 0), W - 1);
        int xc1 = min(max(x0 + 1, 0), W - 1);
        int yc0 = min(max(y0, 0), H - 1);
        int yc1 = min(max(y0 + 1, 0), H - 1);

        const int base = cam * HW;
        const int r0 = base + yc0 * W;
        const int r1 = base + yc1 * W;

        ushort4 u00 = *(const ushort4*)(fm + (size_t)(r0 + xc0) * C_CH + c0);
        ushort4 u10 = *(const ushort4*)(fm + (size_t)(r0 + xc1) * C_CH + c0);
        ushort4 u01 = *(const ushort4*)(fm + (size_t)(r1 + xc0) * C_CH + c0);
        ushort4 u11 = *(const ushort4*)(fm + (size_t)(r1 + xc1) * C_CH + c0);

        float w00 = wx0 * wy0, w10 = wx1 * wy0;
        float w01 = wx0 * wy1, w11 = wx1 * wy1;

        acc.x = fmaf(bf2f(u00.x), w00, acc.x);
        acc.y = fmaf(bf2f(u00.y), w00, acc.y);
        acc.z = fmaf(bf2f(u00.z), w00, acc.z);
        acc.w = fmaf(bf2f(u00.w), w00, acc.w);
        acc.x = fmaf(bf2f(u10.x), w10, acc.x);
        acc.y = fmaf(bf2f(u10.y), w10, acc.y);
        acc.z = fmaf(bf2f(u10.z), w10, acc.z);
        acc.w = fmaf(bf2f(u10.w), w10, acc.w);
        acc.x = fmaf(bf2f(u01.x), w01, acc.x);
        acc.y = fmaf(bf2f(u01.y), w01, acc.y);
        acc.z = fmaf(bf2f(u01.z), w01, acc.z);
        acc.w = fmaf(bf2f(u01.w), w01, acc.w);
        acc.x = fmaf(bf2f(u11.x), w11, acc.x);
        acc.y = fmaf(bf2f(u11.y), w11, acc.y);
        acc.z = fmaf(bf2f(u11.z), w11, acc.z);
        acc.w = fmaf(bf2f(u11.w), w11, acc.w);
    }

    __shared__ float s_part[16][C_CH];
    __shared__ float s_tot[C_CH];
    __shared__ float s_proj[4][C_CH];

    *(float4*)&s_part[wv][c0] = acc;
    __syncthreads();

    if (tid < C_CH) {
        float t = 0.f;
#pragma unroll
        for (int i = 0; i < 16; ++i) t += s_part[i][tid];
        s_tot[tid] = t;
    }
    __syncthreads();

    {
        const int j = tid & (C_CH - 1);
        const int q = tid >> 8;
        const int kb = q * 64;
        float r0s = 0.f, r1s = 0.f, r2s = 0.f, r3s = 0.f;
#pragma unroll 4
        for (int k = kb; k < kb + 64; k += 4) {
            r0s = fmaf(s_tot[k + 0], wproj[(size_t)(k + 0) * C_CH + j], r0s);
            r1s = fmaf(s_tot[k + 1], wproj[(size_t)(k + 1) * C_CH + j], r1s);
            r2s = fmaf(s_tot[k + 2], wproj[(size_t)(k + 2) * C_CH + j], r2s);
            r3s = fmaf(s_tot[k + 3], wproj[(size_t)(k + 3) * C_CH + j], r3s);
        }
        s_proj[q][j] = (r0s + r1s) + (r2s + r3s);
    }
    __syncthreads();

    if (tid < C_CH) {
        float r = (s_proj[0][tid] + s_proj[1][tid]) + (s_proj[2][tid] + s_proj[3][tid])
                  + bproj[tid];
        out[(size_t)a * 512 + tid] = r;
    } else if (tid < 2 * C_CH) {
        const int j = tid - C_CH;
        out[(size_t)a * 512 + C_CH + j] = inst[(size_t)a * C_CH + j];
    }
}

// ---------------- last fallback: fp32 fused ----------------
__global__ __launch_bounds__(1024, 8) void daf_fused_fp32(
    const float* __restrict__ fm0, const float* __restrict__ fm1,
    const float* __restrict__ fm2, const float* __restrict__ fm3,
    const float* __restrict__ pts, const float* __restrict__ wts,
    const float* __restrict__ inst, const float* __restrict__ wproj,
    const float* __restrict__ bproj, float* __restrict__ out)
{
    const int a    = blockIdx.x;
    const int tid  = threadIdx.x;
    const int wv   = tid >> 6;
    const int lane = tid & 63;
    const int level = wv & 3;
    const int chunk = wv >> 2;

    const float* fm; int H, W;
    if (level == 0)      { fm = fm0; H = 64; W = 176; }
    else if (level == 1) { fm = fm1; H = 32; W = 88;  }
    else if (level == 2) { fm = fm2; H = 16; W = 44;  }
    else                 { fm = fm3; H = 8;  W = 22;  }
    const float fW = (float)W, fH = (float)H;
    const int HW = H * W;

    const int c0 = lane << 2;
    const int g  = lane >> 3;

    const float2* __restrict__ pts_a = (const float2*)(pts + (size_t)a * (N_PC * 2));
    const float*  __restrict__ wts_a = wts + (size_t)a * (N_PC * N_LVL * N_GRP);

    const int start = chunk * 20;
    const int end   = (chunk == 3) ? N_PC : (start + 20);

    float4 acc = make_float4(0.f, 0.f, 0.f, 0.f);

#pragma unroll 2
    for (int pc = start; pc < end; ++pc) {
        const int cam = pc % N_CAM;
        float2 pt = pts_a[pc];
        float x = pt.x * fW - 0.5f;
        float y = pt.y * fH - 0.5f;
        float x0f = floorf(x), y0f = floorf(y);
        int   x0 = (int)x0f,  y0 = (int)y0f;
        float wx1 = x - x0f,  wy1 = y - y0f;
        float wx0 = 1.f - wx1, wy0 = 1.f - wy1;
        if (x0 < 0 || x0 >= W)         wx0 = 0.f;
        if (x0 + 1 < 0 || x0 + 1 >= W) wx1 = 0.f;
        if (y0 < 0 || y0 >= H)         wy0 = 0.f;
        if (y0 + 1 < 0 || y0 + 1 >= H) wy1 = 0.f;

        float w = wts_a[pc * (N_LVL * N_GRP) + level * N_GRP + g];
        wx0 *= w; wx1 *= w;

        int xc0 = min(max(x0, 0), W - 1);
        int xc1 = min(max(x0 + 1, 0), W - 1);
        int yc0 = min(max(y0, 0), H - 1);
        int yc1 = min(max(y0 + 1, 0), H - 1);

        const int base = cam * HW;
        const int r0 = base + yc0 * W;
        const int r1 = base + yc1 * W;

        float4 v00 = *(const float4*)(fm + (size_t)(r0 + xc0) * C_CH + c0);
        float4 v10 = *(const float4*)(fm + (size_t)(r0 + xc1) * C_CH + c0);
        float4 v01 = *(const float4*)(fm + (size_t)(r1 + xc0) * C_CH + c0);
        float4 v11 = *(const float4*)(fm + (size_t)(r1 + xc1) * C_CH + c0);

        float w00 = wx0 * wy0, w10 = wx1 * wy0;
        float w01 = wx0 * wy1, w11 = wx1 * wy1;

        acc.x = fmaf(v00.x, w00, acc.x);
        acc.y = fmaf(v00.y, w00, acc.y);
        acc.z = fmaf(v00.z, w00, acc.z);
        acc.w = fmaf(v00.w, w00, acc.w);
        acc.x = fmaf(v10.x, w10, acc.x);
        acc.y = fmaf(v10.y, w10, acc.y);
        acc.z = fmaf(v10.z, w10, acc.z);
        acc.w = fmaf(v10.w, w10, acc.w);
        acc.x = fmaf(v01.x, w01, acc.x);
        acc.y = fmaf(v01.y, w01, acc.y);
        acc.z = fmaf(v01.z, w01, acc.z);
        acc.w = fmaf(v01.w, w01, acc.w);
        acc.x = fmaf(v11.x, w11, acc.x);
        acc.y = fmaf(v11.y, w11, acc.y);
        acc.z = fmaf(v11.z, w11, acc.z);
        acc.w = fmaf(v11.w, w11, acc.w);
    }

    __shared__ float s_part[16][C_CH];
    __shared__ float s_tot[C_CH];
    __shared__ float s_proj[4][C_CH];

    *(float4*)&s_part[wv][c0] = acc;
    __syncthreads();

    if (tid < C_CH) {
        float t = 0.f;
#pragma unroll
        for (int i = 0; i < 16; ++i) t += s_part[i][tid];
        s_tot[tid] = t;
    }
    __syncthreads();

    {
        const int j = tid & (C_CH - 1);
        const int q = tid >> 8;
        const int kb = q * 64;
        float r0s = 0.f, r1s = 0.f, r2s = 0.f, r3s = 0.f;
#pragma unroll 4
        for (int k = kb; k < kb + 64; k += 4) {
            r0s = fmaf(s_tot[k + 0], wproj[(size_t)(k + 0) * C_CH + j], r0s);
            r1s = fmaf(s_tot[k + 1], wproj[(size_t)(k + 1) * C_CH + j], r1s);
            r2s = fmaf(s_tot[k + 2], wproj[(size_t)(k + 2) * C_CH + j], r2s);
            r3s = fmaf(s_tot[k + 3], wproj[(size_t)(k + 3) * C_CH + j], r3s);
        }
        s_proj[q][j] = (r0s + r1s) + (r2s + r3s);
    }
    __syncthreads();

    if (tid < C_CH) {
        float r = (s_proj[0][tid] + s_proj[1][tid]) + (s_proj[2][tid] + s_proj[3][tid])
                  + bproj[tid];
        out[(size_t)a * 512 + tid] = r;
    } else if (tid < 2 * C_CH) {
        const int j = tid - C_CH;
        out[(size_t)a * 512 + C_CH + j] = inst[(size_t)a * C_CH + j];
    }
}

extern "C" void kernel_launch(void* const* d_in, const int* in_sizes, int n_in,
                              void* d_out, int out_size, void* d_ws, size_t ws_size,
                              hipStream_t stream) {
    const float* fm0   = (const float*)d_in[0];
    const float* fm1   = (const float*)d_in[1];
    const float* fm2   = (const float*)d_in[2];
    const float* fm3   = (const float*)d_in[3];
    const float* pts   = (const float*)d_in[4];
    const float* wts   = (const float*)d_in[5];
    const float* inst  = (const float*)d_in[6];
    const float* wproj = (const float*)d_in[7];
    const float* bproj = (const float*)d_in[8];
    float* out = (float*)d_out;

    if (ws_size >= WS_FULL) {
        unsigned short* fmw = (unsigned short*)d_ws;
        float* accb = (float*)((char*)d_ws + FMW_BYTES);

        convert_bf16_kernel<<<2048, 256, 0, stream>>>(fm0, fm1, fm2, fm3, fmw);
        daf_gather_pair<<<A_TOT, 1024, 0, stream>>>(fmw, pts, wts, accb);
        dim3 pg((A_TOT + TM - 1) / TM, 4);
        daf_proj_kernel<<<pg, 256, 0, stream>>>(accb, wproj, bproj, inst, out);
    } else if (ws_size >= WS_MID) {
        unsigned short* fmw = (unsigned short*)d_ws;
        convert_bf16_kernel<<<2048, 256, 0, stream>>>(fm0, fm1, fm2, fm3, fmw);
        daf_fused_bf16<<<A_TOT, 1024, 0, stream>>>(
            fmw, pts, wts, inst, wproj, bproj, out);
    } else {
        daf_fused_fp32<<<A_TOT, 1024, 0, stream>>>(
            fm0, fm1, fm2, fm3, pts, wts, inst, wproj, bproj, out);
    }
}

// Round 9
// 79.115 us; speedup vs baseline: 1.2731x; 1.1736x over previous
//
#include <hip/hip_runtime.h>
#include <hip/hip_bf16.h>

// Sparse4DHead1st deformable aggregation + output_proj + concat.
// Inputs (fp32): fm0..fm3, points_2d, weights, instance_feature, w_proj, b_proj
// Output (fp32): [1, 900, 512] = concat(acc @ w_proj + b, instance_feature)
//
// Round 9: XCD-affinity experiment. Gather block = (anchor, cam), grid 5400,
// blockIdx decoded so each XCD (assuming round-robin dispatch, b%8) sees
// mostly ONE camera's 7.7MB pyramid slice instead of the full 46MB -> L2
// hit rate up, FETCH down. 4-corner ushort4 loads (r5's fastest form).
// Per-cam partials go to acc_cam[900][6][256]; proj sums the 6 cams.

#define A_TOT 900
#define P_PTS 13
#define N_CAM 6
#define C_CH  256
#define N_GRP 8
#define N_LVL 4
#define N_PC  (P_PTS * N_CAM)    // 78

// bf16 fm segment sizes (elements)
#define S0 17301504   // 6*64*176*256
#define S1 4325376    // 6*32*88*256
#define S2 1081344    // 6*16*44*256
#define S3 270336     // 6*8*22*256
#define S_TOT (S0 + S1 + S2 + S3)            // 22,978,560 elts
#define FMW_BYTES ((size_t)S_TOT * 2)        // 45,957,120
#define ACCCAM_BYTES ((size_t)A_TOT * N_CAM * C_CH * 4)  // 5,529,600
#define WS_MID  (FMW_BYTES)
#define WS_FULL (FMW_BYTES + ACCCAM_BYTES)   // 51,486,720

#define TM 8   // anchors per proj m-tile

__device__ __forceinline__ float bf2f(unsigned short u) {
    unsigned int t = ((unsigned int)u) << 16;
    float f;
    __builtin_memcpy(&f, &t, 4);
    return f;
}
__device__ __forceinline__ unsigned short f2b(float x) {
    __hip_bfloat16 h = __float2bfloat16(x);   // RNE
    unsigned short b;
    __builtin_memcpy(&b, &h, 2);
    return b;
}

// ---------------- prepass: fp32 -> bf16 ----------------
__global__ __launch_bounds__(256) void convert_bf16_kernel(
    const float* __restrict__ f0, const float* __restrict__ f1,
    const float* __restrict__ f2, const float* __restrict__ f3,
    unsigned short* __restrict__ out)
{
    const size_t n8 = S_TOT / 8;
    for (size_t i = (size_t)blockIdx.x * blockDim.x + threadIdx.x; i < n8;
         i += (size_t)gridDim.x * blockDim.x) {
        size_t base = i * 8;
        const float* src;
        if (base < S0)                src = f0 + base;
        else if (base < S0 + S1)      src = f1 + (base - S0);
        else if (base < S0 + S1 + S2) src = f2 + (base - S0 - S1);
        else                          src = f3 + (base - S0 - S1 - S2);

        float4 a = *(const float4*)(src);
        float4 b = *(const float4*)(src + 4);
        uint4 o;
        o.x = (unsigned int)f2b(a.x) | ((unsigned int)f2b(a.y) << 16);
        o.y = (unsigned int)f2b(a.z) | ((unsigned int)f2b(a.w) << 16);
        o.z = (unsigned int)f2b(b.x) | ((unsigned int)f2b(b.y) << 16);
        o.w = (unsigned int)f2b(b.z) | ((unsigned int)f2b(b.w) << 16);
        *(uint4*)(out + base) = o;
    }
}

// ---------------- gather: block=(a,cam), wave=level ----------------
__global__ __launch_bounds__(256, 8) void daf_gather_cam(
    const unsigned short* __restrict__ fmw,
    const float* __restrict__ pts, const float* __restrict__ wts,
    float* __restrict__ acc_cam)
{
    // XCD-affinity decode (assumes dispatch round-robins XCD = b % 8):
    //   xcd 0..5 -> cam = xcd, anchors 0..674
    //   xcd 6    -> cams 0..2, anchors 675..899
    //   xcd 7    -> cams 3..5, anchors 675..899
    const int b   = blockIdx.x;
    const int xcd = b & 7;
    const int s   = b >> 3;            // 0..674
    int a, cam;
    if (xcd < 6) { cam = xcd; a = s; }
    else {
        cam = (xcd - 6) * 3 + s / 225;
        a   = 675 + (s % 225);
    }

    const int tid   = threadIdx.x;
    const int level = tid >> 6;        // wave = level
    const int lane  = tid & 63;

    const unsigned short* fm; int H, W;
    if (level == 0)      { fm = fmw;                 H = 64; W = 176; }
    else if (level == 1) { fm = fmw + S0;            H = 32; W = 88;  }
    else if (level == 2) { fm = fmw + S0 + S1;       H = 16; W = 44;  }
    else                 { fm = fmw + S0 + S1 + S2;  H = 8;  W = 22;  }
    const float fW = (float)W, fH = (float)H;
    const int HW = H * W;

    const int c0 = lane << 2;          // 4 channels per lane
    const int g  = lane >> 3;

    // pts[a][p][cam][2]; wts[a][p][cam][level][g]
    const float2* __restrict__ pts_base =
        (const float2*)pts + (size_t)a * N_PC + cam;             // stride N_CAM per p
    const float*  __restrict__ wts_base =
        wts + (((size_t)a * P_PTS * N_CAM + cam) * N_LVL + level) * N_GRP + g;

    float4 acc = make_float4(0.f, 0.f, 0.f, 0.f);

#pragma unroll 2
    for (int p = 0; p < P_PTS; ++p) {
        float2 pt = pts_base[p * N_CAM];
        float x = pt.x * fW - 0.5f;
        float y = pt.y * fH - 0.5f;
        float x0f = floorf(x), y0f = floorf(y);
        int   x0 = (int)x0f,  y0 = (int)y0f;
        float wx1 = x - x0f,  wy1 = y - y0f;
        float wx0 = 1.f - wx1, wy0 = 1.f - wy1;
        if (x0 < 0 || x0 >= W)         wx0 = 0.f;
        if (x0 + 1 < 0 || x0 + 1 >= W) wx1 = 0.f;
        if (y0 < 0 || y0 >= H)         wy0 = 0.f;
        if (y0 + 1 < 0 || y0 + 1 >= H) wy1 = 0.f;

        float w = wts_base[p * (N_CAM * N_LVL * N_GRP)];
        wx0 *= w; wx1 *= w;

        int xc0 = min(max(x0, 0), W - 1);
        int xc1 = min(max(x0 + 1, 0), W - 1);
        int yc0 = min(max(y0, 0), H - 1);
        int yc1 = min(max(y0 + 1, 0), H - 1);

        const int base = cam * HW;
        const int r0 = base + yc0 * W;
        const int r1 = base + yc1 * W;

        ushort4 u00 = *(const ushort4*)(fm + (size_t)(r0 + xc0) * C_CH + c0);
        ushort4 u10 = *(const ushort4*)(fm + (size_t)(r0 + xc1) * C_CH + c0);
        ushort4 u01 = *(const ushort4*)(fm + (size_t)(r1 + xc0) * C_CH + c0);
        ushort4 u11 = *(const ushort4*)(fm + (size_t)(r1 + xc1) * C_CH + c0);

        float w00 = wx0 * wy0, w10 = wx1 * wy0;
        float w01 = wx0 * wy1, w11 = wx1 * wy1;

        acc.x = fmaf(bf2f(u00.x), w00, acc.x);
        acc.y = fmaf(bf2f(u00.y), w00, acc.y);
        acc.z = fmaf(bf2f(u00.z), w00, acc.z);
        acc.w = fmaf(bf2f(u00.w), w00, acc.w);
        acc.x = fmaf(bf2f(u10.x), w10, acc.x);
        acc.y = fmaf(bf2f(u10.y), w10, acc.y);
        acc.z = fmaf(bf2f(u10.z), w10, acc.z);
        acc.w = fmaf(bf2f(u10.w), w10, acc.w);
        acc.x = fmaf(bf2f(u01.x), w01, acc.x);
        acc.y = fmaf(bf2f(u01.y), w01, acc.y);
        acc.z = fmaf(bf2f(u01.z), w01, acc.z);
        acc.w = fmaf(bf2f(u01.w), w01, acc.w);
        acc.x = fmaf(bf2f(u11.x), w11, acc.x);
        acc.y = fmaf(bf2f(u11.y), w11, acc.y);
        acc.z = fmaf(bf2f(u11.z), w11, acc.z);
        acc.w = fmaf(bf2f(u11.w), w11, acc.w);
    }

    // reduce the 4 level-waves, write per-cam partial
    __shared__ float s_part[4][C_CH];
    *(float4*)&s_part[level][c0] = acc;
    __syncthreads();

    // tid 0..255 covers all channels
    float t = s_part[0][tid] + s_part[1][tid] + s_part[2][tid] + s_part[3][tid];
    acc_cam[((size_t)a * N_CAM + cam) * C_CH + tid] = t;
}

// ---------------- proj: out = (sum_cam acc_cam) @ wproj + b, concat inst ----------------
// grid (113 m-tiles, 4 j-tiles), block 256 = 4 waves; wave mg handles 2 anchors.
__global__ __launch_bounds__(256) void daf_proj_kernel(
    const float* __restrict__ acc_cam, const float* __restrict__ wproj,
    const float* __restrict__ bproj, const float* __restrict__ inst,
    float* __restrict__ out)
{
    const int m0 = blockIdx.x * TM;
    const int jt = blockIdx.y;
    const int tid = threadIdx.x;
    const int j  = jt * 64 + (tid & 63);
    const int mg = tid >> 6;             // 0..3
    const int ma = m0 + mg * 2;
    const int mb = ma + 1;
    const int nvalid = min(TM, A_TOT - m0);

    __shared__ float s_acc[TM][C_CH];    // 8 KB

#pragma unroll
    for (int q = 0; q < (TM * C_CH / 4); q += 256) {
        int f4 = q + tid;
        int m  = f4 >> 6;
        int c  = (f4 & 63) << 2;
        float4 v = make_float4(0.f, 0.f, 0.f, 0.f);
        if (m < nvalid) {
            const float* src = acc_cam + (size_t)(m0 + m) * N_CAM * C_CH + c;
#pragma unroll
            for (int cm = 0; cm < N_CAM; ++cm) {
                float4 u = *(const float4*)(src + cm * C_CH);
                v.x += u.x; v.y += u.y; v.z += u.z; v.w += u.w;
            }
        }
        *(float4*)&s_acc[m][c] = v;
    }
    __syncthreads();

    float ra = 0.f, rb = 0.f;
    const int la = mg * 2, lb2 = la + 1;
    for (int kb = 0; kb < C_CH; kb += 4) {
        float w0 = wproj[(size_t)(kb + 0) * C_CH + j];
        float w1 = wproj[(size_t)(kb + 1) * C_CH + j];
        float w2 = wproj[(size_t)(kb + 2) * C_CH + j];
        float w3 = wproj[(size_t)(kb + 3) * C_CH + j];
        float4 a4 = *(const float4*)&s_acc[la][kb];
        float4 b4 = *(const float4*)&s_acc[lb2][kb];
        ra = fmaf(a4.x, w0, ra); ra = fmaf(a4.y, w1, ra);
        ra = fmaf(a4.z, w2, ra); ra = fmaf(a4.w, w3, ra);
        rb = fmaf(b4.x, w0, rb); rb = fmaf(b4.y, w1, rb);
        rb = fmaf(b4.z, w2, rb); rb = fmaf(b4.w, w3, rb);
    }

    const float b = bproj[j];
    if (ma < A_TOT) {
        out[(size_t)ma * 512 + j]         = ra + b;
        out[(size_t)ma * 512 + C_CH + j]  = inst[(size_t)ma * C_CH + j];
    }
    if (mb < A_TOT) {
        out[(size_t)mb * 512 + j]         = rb + b;
        out[(size_t)mb * 512 + C_CH + j]  = inst[(size_t)mb * C_CH + j];
    }
}

// ---------------- mid fallback: r4 fused bf16 (needs only FMW_BYTES) ----------------
__global__ __launch_bounds__(1024, 8) void daf_fused_bf16(
    const unsigned short* __restrict__ fmw,
    const float* __restrict__ pts, const float* __restrict__ wts,
    const float* __restrict__ inst, const float* __restrict__ wproj,
    const float* __restrict__ bproj, float* __restrict__ out)
{
    const int a    = blockIdx.x;
    const int tid  = threadIdx.x;
    const int wv   = tid >> 6;
    const int lane = tid & 63;
    const int level = wv & 3;
    const int chunk = wv >> 2;

    const unsigned short* fm; int H, W;
    if (level == 0)      { fm = fmw;                 H = 64; W = 176; }
    else if (level == 1) { fm = fmw + S0;            H = 32; W = 88;  }
    else if (level == 2) { fm = fmw + S0 + S1;       H = 16; W = 44;  }
    else                 { fm = fmw + S0 + S1 + S2;  H = 8;  W = 22;  }
    const float fW = (float)W, fH = (float)H;
    const int HW = H * W;

    const int c0 = lane << 2;
    const int g  = lane >> 3;

    const float2* __restrict__ pts_a = (const float2*)(pts + (size_t)a * (N_PC * 2));
    const float*  __restrict__ wts_a = wts + (size_t)a * (N_PC * N_LVL * N_GRP);

    const int start = chunk * 20;
    const int end   = (chunk == 3) ? N_PC : (start + 20);

    float4 acc = make_float4(0.f, 0.f, 0.f, 0.f);

#pragma unroll 2
    for (int pc = start; pc < end; ++pc) {
        const int cam = pc % N_CAM;
        float2 pt = pts_a[pc];
        float x = pt.x * fW - 0.5f;
        float y = pt.y * fH - 0.5f;
        float x0f = floorf(x), y0f = floorf(y);
        int   x0 = (int)x0f,  y0 = (int)y0f;
        float wx1 = x - x0f,  wy1 = y - y0f;
        float wx0 = 1.f - wx1, wy0 = 1.f - wy1;
        if (x0 < 0 || x0 >= W)         wx0 = 0.f;
        if (x0 + 1 < 0 || x0 + 1 >= W) wx1 = 0.f;
        if (y0 < 0 || y0 >= H)         wy0 = 0.f;
        if (y0 + 1 < 0 || y0 + 1 >= H) wy1 = 0.f;

        float w = wts_a[pc * (N_LVL * N_GRP) + level * N_GRP + g];
        wx0 *= w; wx1 *= w;

        int xc0 = min(max(x0, 0), W - 1);
        int xc1 = min(max(x0 + 1, 0), W - 1);
        int yc0 = min(max(y0, 0), H - 1);
        int yc1 = min(max(y0 + 1, 0), H - 1);

        const int base = cam * HW;
        const int r0 = base + yc0 * W;
        const int r1 = base + yc1 * W;

        ushort4 u00 = *(const ushort4*)(fm + (size_t)(r0 + xc0) * C_CH + c0);
        ushort4 u10 = *(const ushort4*)(fm + (size_t)(r0 + xc1) * C_CH + c0);
        ushort4 u01 = *(const ushort4*)(fm + (size_t)(r1 + xc0) * C_CH + c0);
        ushort4 u11 = *(const ushort4*)(fm + (size_t)(r1 + xc1) * C_CH + c0);

        float w00 = wx0 * wy0, w10 = wx1 * wy0;
        float w01 = wx0 * wy1, w11 = wx1 * wy1;

        acc.x = fmaf(bf2f(u00.x), w00, acc.x);
        acc.y = fmaf(bf2f(u00.y), w00, acc.y);
        acc.z = fmaf(bf2f(u00.z), w00, acc.z);
        acc.w = fmaf(bf2f(u00.w), w00, acc.w);
        acc.x = fmaf(bf2f(u10.x), w10, acc.x);
        acc.y = fmaf(bf2f(u10.y), w10, acc.y);
        acc.z = fmaf(bf2f(u10.z), w10, acc.z);
        acc.w = fmaf(bf2f(u10.w), w10, acc.w);
        acc.x = fmaf(bf2f(u01.x), w01, acc.x);
        acc.y = fmaf(bf2f(u01.y), w01, acc.y);
        acc.z = fmaf(bf2f(u01.z), w01, acc.z);
        acc.w = fmaf(bf2f(u01.w), w01, acc.w);
        acc.x = fmaf(bf2f(u11.x), w11, acc.x);
        acc.y = fmaf(bf2f(u11.y), w11, acc.y);
        acc.z = fmaf(bf2f(u11.z), w11, acc.z);
        acc.w = fmaf(bf2f(u11.w), w11, acc.w);
    }

    __shared__ float s_part[16][C_CH];
    __shared__ float s_tot[C_CH];
    __shared__ float s_proj[4][C_CH];

    *(float4*)&s_part[wv][c0] = acc;
    __syncthreads();

    if (tid < C_CH) {
        float t = 0.f;
#pragma unroll
        for (int i = 0; i < 16; ++i) t += s_part[i][tid];
        s_tot[tid] = t;
    }
    __syncthreads();

    {
        const int j = tid & (C_CH - 1);
        const int q = tid >> 8;
        const int kb = q * 64;
        float r0s = 0.f, r1s = 0.f, r2s = 0.f, r3s = 0.f;
#pragma unroll 4
        for (int k = kb; k < kb + 64; k += 4) {
            r0s = fmaf(s_tot[k + 0], wproj[(size_t)(k + 0) * C_CH + j], r0s);
            r1s = fmaf(s_tot[k + 1], wproj[(size_t)(k + 1) * C_CH + j], r1s);
            r2s = fmaf(s_tot[k + 2], wproj[(size_t)(k + 2) * C_CH + j], r2s);
            r3s = fmaf(s_tot[k + 3], wproj[(size_t)(k + 3) * C_CH + j], r3s);
        }
        s_proj[q][j] = (r0s + r1s) + (r2s + r3s);
    }
    __syncthreads();

    if (tid < C_CH) {
        float r = (s_proj[0][tid] + s_proj[1][tid]) + (s_proj[2][tid] + s_proj[3][tid])
                  + bproj[tid];
        out[(size_t)a * 512 + tid] = r;
    } else if (tid < 2 * C_CH) {
        const int j = tid - C_CH;
        out[(size_t)a * 512 + C_CH + j] = inst[(size_t)a * C_CH + j];
    }
}

// ---------------- last fallback: fp32 fused ----------------
__global__ __launch_bounds__(1024, 8) void daf_fused_fp32(
    const float* __restrict__ fm0, const float* __restrict__ fm1,
    const float* __restrict__ fm2, const float* __restrict__ fm3,
    const float* __restrict__ pts, const float* __restrict__ wts,
    const float* __restrict__ inst, const float* __restrict__ wproj,
    const float* __restrict__ bproj, float* __restrict__ out)
{
    const int a    = blockIdx.x;
    const int tid  = threadIdx.x;
    const int wv   = tid >> 6;
    const int lane = tid & 63;
    const int level = wv & 3;
    const int chunk = wv >> 2;

    const float* fm; int H, W;
    if (level == 0)      { fm = fm0; H = 64; W = 176; }
    else if (level == 1) { fm = fm1; H = 32; W = 88;  }
    else if (level == 2) { fm = fm2; H = 16; W = 44;  }
    else                 { fm = fm3; H = 8;  W = 22;  }
    const float fW = (float)W, fH = (float)H;
    const int HW = H * W;

    const int c0 = lane << 2;
    const int g  = lane >> 3;

    const float2* __restrict__ pts_a = (const float2*)(pts + (size_t)a * (N_PC * 2));
    const float*  __restrict__ wts_a = wts + (size_t)a * (N_PC * N_LVL * N_GRP);

    const int start = chunk * 20;
    const int end   = (chunk == 3) ? N_PC : (start + 20);

    float4 acc = make_float4(0.f, 0.f, 0.f, 0.f);

#pragma unroll 2
    for (int pc = start; pc < end; ++pc) {
        const int cam = pc % N_CAM;
        float2 pt = pts_a[pc];
        float x = pt.x * fW - 0.5f;
        float y = pt.y * fH - 0.5f;
        float x0f = floorf(x), y0f = floorf(y);
        int   x0 = (int)x0f,  y0 = (int)y0f;
        float wx1 = x - x0f,  wy1 = y - y0f;
        float wx0 = 1.f - wx1, wy0 = 1.f - wy1;
        if (x0 < 0 || x0 >= W)         wx0 = 0.f;
        if (x0 + 1 < 0 || x0 + 1 >= W) wx1 = 0.f;
        if (y0 < 0 || y0 >= H)         wy0 = 0.f;
        if (y0 + 1 < 0 || y0 + 1 >= H) wy1 = 0.f;

        float w = wts_a[pc * (N_LVL * N_GRP) + level * N_GRP + g];
        wx0 *= w; wx1 *= w;

        int xc0 = min(max(x0, 0), W - 1);
        int xc1 = min(max(x0 + 1, 0), W - 1);
        int yc0 = min(max(y0, 0), H - 1);
        int yc1 = min(max(y0 + 1, 0), H - 1);

        const int base = cam * HW;
        const int r0 = base + yc0 * W;
        const int r1 = base + yc1 * W;

        float4 v00 = *(const float4*)(fm + (size_t)(r0 + xc0) * C_CH + c0);
        float4 v10 = *(const float4*)(fm + (size_t)(r0 + xc1) * C_CH + c0);
        float4 v01 = *(const float4*)(fm + (size_t)(r1 + xc0) * C_CH + c0);
        float4 v11 = *(const float4*)(fm + (size_t)(r1 + xc1) * C_CH + c0);

        float w00 = wx0 * wy0, w10 = wx1 * wy0;
        float w01 = wx0 * wy1, w11 = wx1 * wy1;

        acc.x = fmaf(v00.x, w00, acc.x);
        acc.y = fmaf(v00.y, w00, acc.y);
        acc.z = fmaf(v00.z, w00, acc.z);
        acc.w = fmaf(v00.w, w00, acc.w);
        acc.x = fmaf(v10.x, w10, acc.x);
        acc.y = fmaf(v10.y, w10, acc.y);
        acc.z = fmaf(v10.z, w10, acc.z);
        acc.w = fmaf(v10.w, w10, acc.w);
        acc.x = fmaf(v01.x, w01, acc.x);
        acc.y = fmaf(v01.y, w01, acc.y);
        acc.z = fmaf(v01.z, w01, acc.z);
        acc.w = fmaf(v01.w, w01, acc.w);
        acc.x = fmaf(v11.x, w11, acc.x);
        acc.y = fmaf(v11.y, w11, acc.y);
        acc.z = fmaf(v11.z, w11, acc.z);
        acc.w = fmaf(v11.w, w11, acc.w);
    }

    __shared__ float s_part[16][C_CH];
    __shared__ float s_tot[C_CH];
    __shared__ float s_proj[4][C_CH];

    *(float4*)&s_part[wv][c0] = acc;
    __syncthreads();

    if (tid < C_CH) {
        float t = 0.f;
#pragma unroll
        for (int i = 0; i < 16; ++i) t += s_part[i][tid];
        s_tot[tid] = t;
    }
    __syncthreads();

    {
        const int j = tid & (C_CH - 1);
        const int q = tid >> 8;
        const int kb = q * 64;
        float r0s = 0.f, r1s = 0.f, r2s = 0.f, r3s = 0.f;
#pragma unroll 4
        for (int k = kb; k < kb + 64; k += 4) {
            r0s = fmaf(s_tot[k + 0], wproj[(size_t)(k + 0) * C_CH + j], r0s);
            r1s = fmaf(s_tot[k + 1], wproj[(size_t)(k + 1) * C_CH + j], r1s);
            r2s = fmaf(s_tot[k + 2], wproj[(size_t)(k + 2) * C_CH + j], r2s);
            r3s = fmaf(s_tot[k + 3], wproj[(size_t)(k + 3) * C_CH + j], r3s);
        }
        s_proj[q][j] = (r0s + r1s) + (r2s + r3s);
    }
    __syncthreads();

    if (tid < C_CH) {
        float r = (s_proj[0][tid] + s_proj[1][tid]) + (s_proj[2][tid] + s_proj[3][tid])
                  + bproj[tid];
        out[(size_t)a * 512 + tid] = r;
    } else if (tid < 2 * C_CH) {
        const int j = tid - C_CH;
        out[(size_t)a * 512 + C_CH + j] = inst[(size_t)a * C_CH + j];
    }
}

extern "C" void kernel_launch(void* const* d_in, const int* in_sizes, int n_in,
                              void* d_out, int out_size, void* d_ws, size_t ws_size,
                              hipStream_t stream) {
    const float* fm0   = (const float*)d_in[0];
    const float* fm1   = (const float*)d_in[1];
    const float* fm2   = (const float*)d_in[2];
    const float* fm3   = (const float*)d_in[3];
    const float* pts   = (const float*)d_in[4];
    const float* wts   = (const float*)d_in[5];
    const float* inst  = (const float*)d_in[6];
    const float* wproj = (const float*)d_in[7];
    const float* bproj = (const float*)d_in[8];
    float* out = (float*)d_out;

    if (ws_size >= WS_FULL) {
        unsigned short* fmw = (unsigned short*)d_ws;
        float* acc_cam = (float*)((char*)d_ws + FMW_BYTES);

        convert_bf16_kernel<<<2048, 256, 0, stream>>>(fm0, fm1, fm2, fm3, fmw);
        daf_gather_cam<<<A_TOT * N_CAM, 256, 0, stream>>>(fmw, pts, wts, acc_cam);
        dim3 pg((A_TOT + TM - 1) / TM, 4);
        daf_proj_kernel<<<pg, 256, 0, stream>>>(acc_cam, wproj, bproj, inst, out);
    } else if (ws_size >= WS_MID) {
        unsigned short* fmw = (unsigned short*)d_ws;
        convert_bf16_kernel<<<2048, 256, 0, stream>>>(fm0, fm1, fm2, fm3, fmw);
        daf_fused_bf16<<<A_TOT, 1024, 0, stream>>>(
            fmw, pts, wts, inst, wproj, bproj, out);
    } else {
        daf_fused_fp32<<<A_TOT, 1024, 0, stream>>>(
            fm0, fm1, fm2, fm3, pts, wts, inst, wproj, bproj, out);
    }
}